// Round 3
// baseline (750.323 us; speedup 1.0000x reference)
//
#include <hip/hip_runtime.h>
#include <hip/hip_cooperative_groups.h>
#include <math.h>

namespace cg = cooperative_groups;

#define BB 64
#define TT 2048
#define DD 768
#define PP 1024
#define KK 8
#define TSPLIT 32
#define TCHUNK (TT / TSPLIT)   // 64
#define D4 (DD / 4)            // 192
#define GRID_F 256             // cooperative grid blocks

// ---------------------------------------------------------------------------
// ws layout (4-byte units):
//   partial : float[TSPLIT*BB*DD] = 1572864
//   xmean   : float[BB*DD]        = 49152
//   xproj   : float[BB*DD]        = 49152
//   xss     : float[BB]           = 64
//   counts  : int  [PP]           = 1024
//   pscale  : float[PP]           = 1024
//   sim     : float[BB*PP]        = 65536
//   major   : int  [KK]           = 8
// ---------------------------------------------------------------------------

__device__ __forceinline__ float wave_sum(float v) {
    for (int off = 32; off > 0; off >>= 1) v += __shfl_down(v, off, 64);
    return v;
}

// order-preserving float->uint map (monotone for all non-NaN floats)
__device__ __forceinline__ unsigned int fmap(float f) {
    unsigned int b = __float_as_uint(f);
    return (b & 0x80000000u) ? ~b : (b | 0x80000000u);
}

// K1: partial max over token chunks, plain stores.  grid (TSPLIT, BB), block 192.
__global__ __launch_bounds__(192) void k_maxpart(const float* __restrict__ x,
                                                 float* __restrict__ partial) {
    const int chunk = blockIdx.x, b = blockIdx.y, d4 = threadIdx.x;
    const float4* x4 = (const float4*)x;
    size_t base = ((size_t)b * TT + (size_t)chunk * TCHUNK) * D4 + d4;
    float4 m = make_float4(-INFINITY, -INFINITY, -INFINITY, -INFINITY);
    #pragma unroll 8
    for (int t = 0; t < TCHUNK; ++t) {
        float4 v = x4[base + (size_t)t * D4];
        m.x = fmaxf(m.x, v.x); m.y = fmaxf(m.y, v.y);
        m.z = fmaxf(m.z, v.z); m.w = fmaxf(m.w, v.w);
    }
    ((float4*)partial)[((size_t)chunk * BB + b) * D4 + d4] = m;
}

// K2: everything else, one cooperative kernel.  grid 256, block 256.
__global__ __launch_bounds__(256) void k_fused(const float* __restrict__ partial,
                                               const float* __restrict__ prompt,
                                               const float* __restrict__ W,
                                               float* __restrict__ xmean,
                                               float* __restrict__ xproj,
                                               float* __restrict__ xss,
                                               int* __restrict__ counts,
                                               float* __restrict__ pscale,
                                               float* __restrict__ sim,
                                               int* __restrict__ major,
                                               float* __restrict__ out) {
    cg::grid_group grid = cg::this_grid();
    const int blk = blockIdx.x, tid = threadIdx.x;
    const int lane = tid & 63, wave = tid >> 6;

    __shared__ unsigned long long s_u64[PP];       // 8 KB, aliased per phase
    __shared__ unsigned long long s_wmax[4];
    __shared__ float s_wf[4];
    __shared__ int s_sel[KK];
    __shared__ int s_maj[KK];
    float* s_f = (float*)s_u64;                    // 768-float row buffer alias

    // ---- Phase A: zero counts/xss; reduce partials -> xmean; pscale ----
    if (blk == 0) {
        for (int i = tid; i < PP + BB; i += 256) {
            if (i < PP) counts[i] = 0;
            else xss[i - PP] = 0.f;
        }
    }
    {
        int i = blk * 256 + tid;                   // scalar float index < BB*DD
        if (i < BB * DD) {
            float m = partial[i];
            #pragma unroll 8
            for (int c = 1; c < TSPLIT; ++c) m = fmaxf(m, partial[(size_t)c * (BB * DD) + i]);
            xmean[i] = m;
        }
    }
    {
        const int p = blk * 4 + wave;              // one wave per prompt row
        const float4* r = (const float4*)(prompt + (size_t)p * DD);
        float ss = 0.f;
        for (int j = 0; j < 3; ++j) {
            float4 v = r[j * 64 + lane];
            ss += v.x * v.x + v.y * v.y + v.z * v.z + v.w * v.w;
        }
        ss = wave_sum(ss);
        if (lane == 0) pscale[p] = 1.0f / sqrtf(fmaxf(ss, 1e-12f));
    }
    grid.sync();

    // ---- Phase B: xproj = xmean @ W^T  (+ xss row sum-of-squares) ----
    {
        const int b = blk >> 2, o0 = (blk & 3) * 192;
        for (int i = tid; i < DD; i += 256) s_f[i] = xmean[b * DD + i];
        __syncthreads();
        const float4* xm4 = (const float4*)s_f;
        float sacc = 0.f;
        for (int k = 0; k < 48; ++k) {
            const int o = o0 + 4 * k + wave;
            const float4* w4 = (const float4*)(W + (size_t)o * DD);
            float acc = 0.f;
            for (int j = 0; j < 3; ++j) {
                float4 a = xm4[j * 64 + lane];
                float4 w = w4[j * 64 + lane];
                acc += a.x * w.x + a.y * w.y + a.z * w.z + a.w * w.w;
            }
            acc = wave_sum(acc);
            if (lane == 0) {
                xproj[b * DD + o] = acc;
                sacc += acc * acc;
            }
        }
        if (lane == 0) s_wf[wave] = sacc;
        __syncthreads();
        if (tid == 0) atomicAdd(&xss[b], s_wf[0] + s_wf[1] + s_wf[2] + s_wf[3]);
    }
    grid.sync();

    // ---- Phase C: sim[b,p] = dot(xproj[b], prompt[p]) * rsqrt(xss[b]) * pscale[p] ----
    {
        const int b = blk >> 2, p0 = (blk & 3) * 256;
        for (int i = tid; i < DD; i += 256) s_f[i] = xproj[b * DD + i];
        __syncthreads();
        const float xs = 1.0f / sqrtf(fmaxf(xss[b], 1e-12f));
        const float4* xp4 = (const float4*)s_f;
        for (int k = 0; k < 64; ++k) {
            const int p = p0 + 4 * k + wave;
            const float4* pr4 = (const float4*)(prompt + (size_t)p * DD);
            float acc = 0.f;
            for (int j = 0; j < 3; ++j) {
                float4 a = xp4[j * 64 + lane];
                float4 v = pr4[j * 64 + lane];
                acc += a.x * v.x + a.y * v.y + a.z * v.z + a.w * v.w;
            }
            acc = wave_sum(acc);
            if (lane == 0) sim[b * PP + p] = acc * xs * pscale[p];
        }
    }
    grid.sync();

    // ---- Phase D: per-row top-8 (ties -> lowest index) + bincount ----
    if (blk < BB) {
        const int b = blk;
        __syncthreads();   // s_f -> s_u64 reuse
        for (int p = tid; p < PP; p += 256)
            s_u64[p] = ((unsigned long long)fmap(sim[b * PP + p]) << 32)
                     | (unsigned int)(PP - 1 - p);
        __syncthreads();
        for (int it = 0; it < KK; ++it) {
            unsigned long long mk = 0;
            for (int p = tid; p < PP; p += 256) {
                unsigned long long v = s_u64[p];
                if (v > mk) mk = v;
            }
            for (int off = 32; off > 0; off >>= 1) {
                unsigned long long o = __shfl_down(mk, off, 64);
                if (o > mk) mk = o;
            }
            if (lane == 0) s_wmax[wave] = mk;
            __syncthreads();
            if (tid == 0) {
                unsigned long long m = s_wmax[0];
                for (int w = 1; w < 4; ++w) if (s_wmax[w] > m) m = s_wmax[w];
                int p = PP - 1 - (int)(m & 0xFFFFFFFFu);
                s_sel[it] = p;
                s_u64[p] = 0ull;
            }
            __syncthreads();
        }
        if (tid < KK) atomicAdd(&counts[s_sel[tid]], 1);
    }
    grid.sync();

    // ---- Phase E: top-8 of counts (ties -> lowest id), block 0 only ----
    if (blk == 0) {
        for (int p = tid; p < PP; p += 256)
            s_u64[p] = ((unsigned long long)(unsigned int)counts[p] << 32)
                     | (unsigned int)(PP - 1 - p);
        __syncthreads();
        for (int it = 0; it < KK; ++it) {
            unsigned long long mk = 0;
            for (int p = tid; p < PP; p += 256) {
                unsigned long long v = s_u64[p];
                if (v > mk) mk = v;
            }
            for (int off = 32; off > 0; off >>= 1) {
                unsigned long long o = __shfl_down(mk, off, 64);
                if (o > mk) mk = o;
            }
            if (lane == 0) s_wmax[wave] = mk;
            __syncthreads();
            if (tid == 0) {
                unsigned long long m = s_wmax[0];
                for (int w = 1; w < 4; ++w) if (s_wmax[w] > m) m = s_wmax[w];
                int p = PP - 1 - (int)(m & 0xFFFFFFFFu);
                major[it] = p;
                s_u64[p] = 0ull;
            }
            __syncthreads();
        }
    }
    grid.sync();

    // ---- Phase F: gather batched_prompt + reduce_sim ----
    if (tid < KK) s_maj[tid] = major[tid];
    __syncthreads();
    {
        // 393216 output floats, 1536 per block (scalar: out+1 breaks 16B alignment)
        const int i0 = blk * 1536;
        #pragma unroll
        for (int j = 0; j < 6; ++j) {
            const int i = i0 + j * 256 + tid;
            const int pair = i / DD;           // (b*KK + k)
            const int d = i - pair * DD;
            out[1 + i] = prompt[(size_t)s_maj[pair & 7] * DD + d];
        }
    }
    if (blk == 0) {
        float s = 0.f;
        for (int i = tid; i < BB * KK; i += 256) {
            const int b = i >> 3, k = i & 7;
            s += sim[b * PP + s_maj[k]];
        }
        s = wave_sum(s);
        if (lane == 0) s_wf[wave] = s;
        __syncthreads();
        if (tid == 0) out[0] = (s_wf[0] + s_wf[1] + s_wf[2] + s_wf[3]) / (float)BB;
    }
}

extern "C" void kernel_launch(void* const* d_in, const int* in_sizes, int n_in,
                              void* d_out, int out_size, void* d_ws, size_t ws_size,
                              hipStream_t stream) {
    const float* x      = (const float*)d_in[0];   // [64,2048,768]
    const float* prompt = (const float*)d_in[1];   // [1024,768]
    const float* W      = (const float*)d_in[2];   // [768,768]
    float* out = (float*)d_out;

    float* ws      = (float*)d_ws;
    float* partial = ws;                              // 1572864
    float* xmean   = partial + TSPLIT * BB * DD;      // 49152
    float* xproj   = xmean + BB * DD;                 // 49152
    float* xss     = xproj + BB * DD;                 // 64
    int*   counts  = (int*)(xss + BB);                // 1024
    float* pscale  = (float*)(counts + PP);           // 1024
    float* sim     = pscale + PP;                     // 65536
    int*   major   = (int*)(sim + BB * PP);           // 8

    k_maxpart<<<dim3(TSPLIT, BB), 192, 0, stream>>>(x, partial);

    void* args[] = {&partial, &prompt, &W, &xmean, &xproj, &xss,
                    &counts, &pscale, &sim, &major, &out};
    hipLaunchCooperativeKernel((const void*)k_fused, dim3(GRID_F), dim3(256),
                               args, 0, stream);
}